// Round 3
// baseline (137.255 us; speedup 1.0000x reference)
//
#include <hip/hip_runtime.h>

// Problem constants (from reference): N=4096, D=512, C=100, P=64
#define D 512
#define D4 (D / 4)      // 128 float4 chunks per row
#define P 64
#define WPB 4           // waves per block
#define NB 2            // boxes per group (same class)
#define MAXC 256        // LDS histogram capacity (C=100)
#define EPS_COS 1e-8f
#define EPS_INV 1e-5f

__device__ __forceinline__ float wave_sum(float v) {
#pragma unroll
    for (int m = 32; m >= 1; m >>= 1) v += __shfl_xor(v, m, 64);
    return v;
}

// Fused prep:
//   blocks [0, normBlocks)                : pp[r] = ||protos[r]||^2
//   blocks [normBlocks, normBlocks+trBlk) : transpose protos -> protosT[c][d4][p][4]
//   block  normBlocks+trBlk               : counting-sort boxes into NB-groups
__global__ __launch_bounds__(256) void prep_kernel(
    const float* __restrict__ protos, float* __restrict__ pp,
    float* __restrict__ protosT, int rows,
    const int* __restrict__ cls_ids, int* __restrict__ slots,
    int* __restrict__ gcount, int N, int C, int normBlocks, int trBlocks)
{
    const int bid  = blockIdx.x;
    const int lane = threadIdx.x & 63;
    const int wave = threadIdx.x >> 6;

    if (bid < normBlocks) {
        const int r = bid * WPB + wave;
        if (r >= rows) return;
        const float* row = protos + (size_t)r * D;
        const float4 a = *(const float4*)(row + lane * 4);
        const float4 b = *(const float4*)(row + 256 + lane * 4);
        float s = a.x*a.x + a.y*a.y + a.z*a.z + a.w*a.w
                + b.x*b.x + b.y*b.y + b.z*b.z + b.w*b.w;
        s = wave_sum(s);
        if (lane == 0) pp[r] = s;
        return;
    }

    if (bid < normBlocks + trBlocks) {
        // one wave per (class c, d4): lane p reads protos[c][p][4*d4..+3] (16B
        // strided 2KB -> lines reused by neighboring d4 waves via L2/L3),
        // writes protosT[((c*D4+d4)*P+p)*4 ..] coalesced (1KB/wave).
        const int idx = (bid - normBlocks) * WPB + wave;
        if (idx >= C * D4) return;
        const int c  = idx >> 7;          // / D4
        const int d4 = idx & (D4 - 1);
        const float4 v = *(const float4*)(protos + (size_t)(c * P + lane) * D + 4 * d4);
        *(float4*)(protosT + ((size_t)(c * D4 + d4) * P + lane) * 4) = v;
        return;
    }

    // ---- build path: single block, 256 threads ----
    __shared__ int cnt[MAXC], bas[MAXC], fil[MAXC];
    __shared__ int sv[256];
    const int tid = threadIdx.x;
    for (int c = tid; c < MAXC; c += 256) { cnt[c] = 0; fil[c] = 0; }
    __syncthreads();
    for (int n = tid; n < N; n += 256) atomicAdd(&cnt[cls_ids[n]], 1);
    __syncthreads();
    int v = 0;
    if (tid < C) v = (cnt[tid] + NB - 1) / NB;
    sv[tid] = v;
    __syncthreads();
#pragma unroll
    for (int off = 1; off < 256; off <<= 1) {
        const int t = (tid >= off) ? sv[tid - off] : 0;
        __syncthreads();
        sv[tid] += t;
        __syncthreads();
    }
    const int G = sv[255];                 // total groups
    if (tid < C) bas[tid] = sv[tid] - v;   // exclusive scan
    if (tid == 0) gcount[0] = G;
    __syncthreads();
    for (int i = tid; i < G * NB; i += 256) slots[i] = -1;
    __syncthreads();
    for (int n = tid; n < N; n += 256) {
        const int c = cls_ids[n];
        const int p = atomicAdd(&fil[c], 1);
        slots[bas[c] * NB + p] = n;
    }
}

__device__ __forceinline__ void box_epilogue(
    float r_dot, float r_l1, float ff, float s_pp, int myp,
    float& prob_o, int& bidx_o)
{
    const float fnorm = fmaxf(sqrtf(ff),   EPS_COS);
    const float pnorm = fmaxf(sqrtf(s_pp), EPS_COS);
    const float d_cos = 1.0f - r_dot / (fnorm * pnorm);
    const float d_l1  = r_l1 * (1.0f / (float)D);
    const float d_l2  = (ff - 2.0f * r_dot + s_pp) * (1.0f / (float)D);

    float s[3];
    s[0] = 1.0f / (d_cos + EPS_INV);
    s[1] = 1.0f / (d_l1  + EPS_INV);
    s[2] = 1.0f / (d_l2  + EPS_INV);

    float prob = 0.f;
#pragma unroll
    for (int i = 0; i < 3; ++i) {
        float m = s[i];
#pragma unroll
        for (int w = 32; w >= 1; w >>= 1) m = fmaxf(m, __shfl_xor(m, w, 64));
        const float e = expf(s[i] - m);
        const float denom = wave_sum(e);
        prob += e / denom;
    }
    prob *= (1.0f / 3.0f);

    // argmax over protos, first-index tie-break
    float best = prob;
    int   bidx = myp;
#pragma unroll
    for (int w = 32; w >= 1; w >>= 1) {
        const float ov = __shfl_xor(best, w, 64);
        const int   oi = __shfl_xor(bidx, w, 64);
        if (ov > best || (ov == best && oi < bidx)) { best = ov; bidx = oi; }
    }
    prob_o = prob;
    bidx_o = bidx;
}

// Main kernel: one wave per NB=2 same-class boxes; LANE p OWNS PROTO p.
// Loop over d4: coalesced float4 of 64 protos' chunk from protosT + two
// wave-uniform (scalar) feat chunks. No cross-lane ops in the hot loop.
__global__ __launch_bounds__(WPB * 64) void proto_probs_kernel(
    const float* __restrict__ feats,        // [N, D]
    const float* __restrict__ protosT,      // [C][D4][P][4]
    const int*   __restrict__ cls_ids,      // [N]
    const int*   __restrict__ proto_labels, // [C, P]
    const float* __restrict__ ppbuf,        // [C*P] ||p||^2
    const int*   __restrict__ slots,        // [G*NB] box ids (-1 pad)
    const int*   __restrict__ gcount,       // [1] G
    float* __restrict__ out,                // [N] labels ++ [N, P] probs
    int N)
{
    const int lane = threadIdx.x & 63;
    const int wave = threadIdx.x >> 6;

    // Bijective chunked XCD swizzle (m204): class runs stay on one XCD's L2.
    const int nbk = gridDim.x;
    const int q   = nbk >> 3, r = nbk & 7;
    const int xcd = blockIdx.x & 7, bix = blockIdx.x >> 3;
    const int swz = (xcd < r ? xcd * (q + 1) : r * (q + 1) + (xcd - r) * q) + bix;

    const int g = swz * WPB + wave;
    if (g >= gcount[0]) return;

    const int b0 = __builtin_amdgcn_readfirstlane(slots[NB * g]);
    const int b1 = __builtin_amdgcn_readfirstlane(slots[NB * g + 1]);
    const bool v1 = (b1 >= 0);
    const int n0 = b0;
    const int n1 = v1 ? b1 : b0;
    const int cls = __builtin_amdgcn_readfirstlane(cls_ids[n0]);

    const float* fA = feats   + (size_t)n0 * D;
    const float* fB = feats   + (size_t)n1 * D;
    const float* pT = protosT + (size_t)cls * (D4 * P * 4);

    // feat self-norms (distributed coalesced read + one wave reduction each)
    float ffA, ffB;
    {
        const float4 a0 = *(const float4*)(fA + lane * 4);
        const float4 a1 = *(const float4*)(fA + 256 + lane * 4);
        ffA = wave_sum(a0.x*a0.x + a0.y*a0.y + a0.z*a0.z + a0.w*a0.w
                     + a1.x*a1.x + a1.y*a1.y + a1.z*a1.z + a1.w*a1.w);
        const float4 c0 = *(const float4*)(fB + lane * 4);
        const float4 c1 = *(const float4*)(fB + 256 + lane * 4);
        ffB = wave_sum(c0.x*c0.x + c0.y*c0.y + c0.z*c0.z + c0.w*c0.w
                     + c1.x*c1.x + c1.y*c1.y + c1.z*c1.z + c1.w*c1.w);
    }

    float dotA = 0.f, l1A = 0.f, dotB = 0.f, l1B = 0.f;
#pragma unroll 8
    for (int d4 = 0; d4 < D4; ++d4) {
        const float4 qv = *(const float4*)(pT + (size_t)(d4 * P + lane) * 4);
        const float4 av = *(const float4*)(fA + 4 * d4);   // wave-uniform
        const float4 bv = *(const float4*)(fB + 4 * d4);   // wave-uniform
        float t;
        dotA += av.x*qv.x; t = av.x - qv.x; l1A += fabsf(t);
        dotA += av.y*qv.y; t = av.y - qv.y; l1A += fabsf(t);
        dotA += av.z*qv.z; t = av.z - qv.z; l1A += fabsf(t);
        dotA += av.w*qv.w; t = av.w - qv.w; l1A += fabsf(t);
        dotB += bv.x*qv.x; t = bv.x - qv.x; l1B += fabsf(t);
        dotB += bv.y*qv.y; t = bv.y - qv.y; l1B += fabsf(t);
        dotB += bv.z*qv.z; t = bv.z - qv.z; l1B += fabsf(t);
        dotB += bv.w*qv.w; t = bv.w - qv.w; l1B += fabsf(t);
    }

    const float s_pp = ppbuf[cls * P + lane];   // lane p owns proto p

    float probA; int bidxA;
    box_epilogue(dotA, l1A, ffA, s_pp, lane, probA, bidxA);
    out[(size_t)N + (size_t)n0 * P + lane] = probA;
    if (lane == 0) out[n0] = (float)proto_labels[cls * P + bidxA];

    if (v1) {
        float probB; int bidxB;
        box_epilogue(dotB, l1B, ffB, s_pp, lane, probB, bidxB);
        out[(size_t)N + (size_t)n1 * P + lane] = probB;
        if (lane == 0) out[n1] = (float)proto_labels[cls * P + bidxB];
    }
}

extern "C" void kernel_launch(void* const* d_in, const int* in_sizes, int n_in,
                              void* d_out, int out_size, void* d_ws, size_t ws_size,
                              hipStream_t stream) {
    const float* feats        = (const float*)d_in[0];
    const float* protos       = (const float*)d_in[1];
    const int*   cls_ids      = (const int*)d_in[2];
    const int*   proto_labels = (const int*)d_in[3];
    float* out = (float*)d_out;

    const int N    = in_sizes[2];           // 4096
    const int rows = in_sizes[1] / D;       // C*P = 6400
    const int C    = rows / P;              // 100
    const int Gmax = (N + C * (NB - 1)) / NB;

    // Workspace: pp[rows] f32 | gcount[1] | slots[Gmax*NB] | pad | protosT[C*D*P]
    float* pp     = (float*)d_ws;
    int*   gcount = (int*)(pp + rows);
    int*   slots  = gcount + 1;
    size_t off = (size_t)rows * 4 + 4 + (size_t)Gmax * NB * 4;
    off = (off + 255) & ~(size_t)255;
    float* protosT = (float*)((char*)d_ws + off);

    const int normBlocks = (rows + WPB - 1) / WPB;        // 1600
    const int trBlocks   = (C * D4 + WPB - 1) / WPB;      // 3200
    const int mainBlocks = (Gmax + WPB - 1) / WPB;        // 525

    prep_kernel<<<normBlocks + trBlocks + 1, 256, 0, stream>>>(
        protos, pp, protosT, rows, cls_ids, slots, gcount, N, C,
        normBlocks, trBlocks);
    proto_probs_kernel<<<mainBlocks, WPB * 64, 0, stream>>>(
        feats, protosT, cls_ids, proto_labels, pp, slots, gcount, out, N);
}

// Round 4
// 116.135 us; speedup vs baseline: 1.1819x; 1.1819x over previous
//
#include <hip/hip_runtime.h>

// Problem constants (from reference): N=4096, D=512, C=100, P=64
#define D 512
#define D4 (D / 4)      // 128 float4 chunks per row
#define P 64
#define WPB 4           // waves per block
#define NB 2            // boxes per group (same class)
#define MAXC 256        // LDS histogram capacity (C=100)
#define EPS_COS 1e-8f
#define EPS_INV 1e-5f

__device__ __forceinline__ float wave_sum(float v) {
#pragma unroll
    for (int m = 32; m >= 1; m >>= 1) v += __shfl_xor(v, m, 64);
    return v;
}

// Fused prep:
//   blocks [0, normBlocks) : pp[r] = ||protos[r]||^2 AND transposed copy
//                            protosT[c][d4][p][4] (same row read serves both)
//   block  normBlocks      : counting-sort boxes into NB-groups
__global__ __launch_bounds__(256) void prep_kernel(
    const float* __restrict__ protos, float* __restrict__ pp,
    float* __restrict__ protosT, int rows,
    const int* __restrict__ cls_ids, int* __restrict__ slots,
    int* __restrict__ gcount, int N, int C, int normBlocks)
{
    const int bid  = blockIdx.x;
    const int lane = threadIdx.x & 63;
    const int wave = threadIdx.x >> 6;

    if (bid < normBlocks) {
        const int r = bid * WPB + wave;
        if (r >= rows) return;
        const int c = r >> 6;          // class
        const int p = r & 63;          // proto within class
        const float* row = protos + (size_t)r * D;
        const float4 a = *(const float4*)(row + lane * 4);        // chunk lane
        const float4 b = *(const float4*)(row + 256 + lane * 4);  // chunk 64+lane
        // transposed copy: protosT[(c*D4 + d4)*P + p] (float4 granules)
        float4* pT4 = (float4*)protosT + (size_t)c * (D4 * P);
        pT4[lane * P + p] = a;
        pT4[(64 + lane) * P + p] = b;
        float s = a.x*a.x + a.y*a.y + a.z*a.z + a.w*a.w
                + b.x*b.x + b.y*b.y + b.z*b.z + b.w*b.w;
        s = wave_sum(s);
        if (lane == 0) pp[r] = s;
        return;
    }

    // ---- build path: single block, 256 threads ----
    __shared__ int cnt[MAXC], bas[MAXC], fil[MAXC];
    __shared__ int sv[256];
    const int tid = threadIdx.x;
    for (int c = tid; c < MAXC; c += 256) { cnt[c] = 0; fil[c] = 0; }
    __syncthreads();
    for (int n = tid; n < N; n += 256) atomicAdd(&cnt[cls_ids[n]], 1);
    __syncthreads();
    int v = 0;
    if (tid < C) v = (cnt[tid] + NB - 1) / NB;
    sv[tid] = v;
    __syncthreads();
#pragma unroll
    for (int off = 1; off < 256; off <<= 1) {
        const int t = (tid >= off) ? sv[tid - off] : 0;
        __syncthreads();
        sv[tid] += t;
        __syncthreads();
    }
    const int G = sv[255];                 // total groups
    if (tid < C) bas[tid] = sv[tid] - v;   // exclusive scan
    if (tid == 0) gcount[0] = G;
    __syncthreads();
    for (int i = tid; i < G * NB; i += 256) slots[i] = -1;
    __syncthreads();
    for (int n = tid; n < N; n += 256) {
        const int c = cls_ids[n];
        const int p = atomicAdd(&fil[c], 1);
        slots[bas[c] * NB + p] = n;
    }
}

__device__ __forceinline__ void box_epilogue(
    float r_dot, float r_l1, float ff, float s_pp, int myp,
    float& prob_o, int& bidx_o)
{
    const float fnorm = fmaxf(sqrtf(ff),   EPS_COS);
    const float pnorm = fmaxf(sqrtf(s_pp), EPS_COS);
    const float d_cos = 1.0f - r_dot / (fnorm * pnorm);
    const float d_l1  = r_l1 * (1.0f / (float)D);
    const float d_l2  = (ff - 2.0f * r_dot + s_pp) * (1.0f / (float)D);

    float s[3];
    s[0] = 1.0f / (d_cos + EPS_INV);
    s[1] = 1.0f / (d_l1  + EPS_INV);
    s[2] = 1.0f / (d_l2  + EPS_INV);

    float prob = 0.f;
#pragma unroll
    for (int i = 0; i < 3; ++i) {
        float m = s[i];
#pragma unroll
        for (int w = 32; w >= 1; w >>= 1) m = fmaxf(m, __shfl_xor(m, w, 64));
        const float e = expf(s[i] - m);
        const float denom = wave_sum(e);
        prob += e / denom;
    }
    prob *= (1.0f / 3.0f);

    // argmax over protos, first-index tie-break
    float best = prob;
    int   bidx = myp;
#pragma unroll
    for (int w = 32; w >= 1; w >>= 1) {
        const float ov = __shfl_xor(best, w, 64);
        const int   oi = __shfl_xor(bidx, w, 64);
        if (ov > best || (ov == best && oi < bidx)) { best = ov; bidx = oi; }
    }
    prob_o = prob;
    bidx_o = bidx;
}

// Main kernel: one wave per NB=2 same-class boxes; LANE p OWNS PROTO p.
// D processed in 16 chunks of 8 float4s with explicit double-buffering:
// next chunk's loads (8 vector + 16 uniform) issue BEFORE current chunk's
// ~192 VALU ops -> MLP ~8-24, hides L2/L3 latency (round-3 had VGPR=16, MLP~1).
__global__ __launch_bounds__(WPB * 64) void proto_probs_kernel(
    const float* __restrict__ feats,        // [N, D]
    const float* __restrict__ protosT,      // [C][D4][P][4]
    const int*   __restrict__ cls_ids,      // [N]
    const int*   __restrict__ proto_labels, // [C, P]
    const float* __restrict__ ppbuf,        // [C*P] ||p||^2
    const int*   __restrict__ slots,        // [G*NB] box ids (-1 pad)
    const int*   __restrict__ gcount,       // [1] G
    float* __restrict__ out,                // [N] labels ++ [N, P] probs
    int N)
{
    const int lane = threadIdx.x & 63;
    const int wave = threadIdx.x >> 6;

    // Bijective chunked XCD swizzle (m204): class runs stay on one XCD's L2.
    const int nbk = gridDim.x;
    const int q   = nbk >> 3, r = nbk & 7;
    const int xcd = blockIdx.x & 7, bix = blockIdx.x >> 3;
    const int swz = (xcd < r ? xcd * (q + 1) : r * (q + 1) + (xcd - r) * q) + bix;

    const int g = swz * WPB + wave;
    if (g >= gcount[0]) return;

    const int b0 = __builtin_amdgcn_readfirstlane(slots[NB * g]);
    const int b1 = __builtin_amdgcn_readfirstlane(slots[NB * g + 1]);
    const bool v1 = (b1 >= 0);
    const int n0 = b0;
    const int n1 = v1 ? b1 : b0;
    const int cls = __builtin_amdgcn_readfirstlane(cls_ids[n0]);

    const float*  fA  = feats + (size_t)n0 * D;
    const float*  fB  = feats + (size_t)n1 * D;
    const float4* fA4 = (const float4*)fA;
    const float4* fB4 = (const float4*)fB;
    const float4* pT4 = (const float4*)protosT + (size_t)cls * (D4 * P);

    // feat self-norms (distributed coalesced read + one wave reduction each)
    float ffA, ffB;
    {
        const float4 a0 = *(const float4*)(fA + lane * 4);
        const float4 a1 = *(const float4*)(fA + 256 + lane * 4);
        ffA = wave_sum(a0.x*a0.x + a0.y*a0.y + a0.z*a0.z + a0.w*a0.w
                     + a1.x*a1.x + a1.y*a1.y + a1.z*a1.z + a1.w*a1.w);
        const float4 c0 = *(const float4*)(fB + lane * 4);
        const float4 c1 = *(const float4*)(fB + 256 + lane * 4);
        ffB = wave_sum(c0.x*c0.x + c0.y*c0.y + c0.z*c0.z + c0.w*c0.w
                     + c1.x*c1.x + c1.y*c1.y + c1.z*c1.z + c1.w*c1.w);
    }

    float dotA = 0.f, l1A = 0.f, dotB = 0.f, l1B = 0.f;

    float4 qc[8], ac[8], bc[8];
#pragma unroll
    for (int j = 0; j < 8; ++j) qc[j] = pT4[j * P + lane];
#pragma unroll
    for (int j = 0; j < 8; ++j) { ac[j] = fA4[j]; bc[j] = fB4[j]; }

#pragma unroll 1
    for (int c = 0; c < 16; ++c) {
        float4 qn[8], an[8], bn[8];
        const int nc = (c + 1) & 15;   // last iter reloads chunk 0 (in-bounds, unused)
#pragma unroll
        for (int j = 0; j < 8; ++j) qn[j] = pT4[(nc * 8 + j) * P + lane];
#pragma unroll
        for (int j = 0; j < 8; ++j) { an[j] = fA4[nc * 8 + j]; bn[j] = fB4[nc * 8 + j]; }
#pragma unroll
        for (int j = 0; j < 8; ++j) {
            float t;
            dotA += ac[j].x*qc[j].x; t = ac[j].x - qc[j].x; l1A += fabsf(t);
            dotA += ac[j].y*qc[j].y; t = ac[j].y - qc[j].y; l1A += fabsf(t);
            dotA += ac[j].z*qc[j].z; t = ac[j].z - qc[j].z; l1A += fabsf(t);
            dotA += ac[j].w*qc[j].w; t = ac[j].w - qc[j].w; l1A += fabsf(t);
            dotB += bc[j].x*qc[j].x; t = bc[j].x - qc[j].x; l1B += fabsf(t);
            dotB += bc[j].y*qc[j].y; t = bc[j].y - qc[j].y; l1B += fabsf(t);
            dotB += bc[j].z*qc[j].z; t = bc[j].z - qc[j].z; l1B += fabsf(t);
            dotB += bc[j].w*qc[j].w; t = bc[j].w - qc[j].w; l1B += fabsf(t);
        }
#pragma unroll
        for (int j = 0; j < 8; ++j) { qc[j] = qn[j]; ac[j] = an[j]; bc[j] = bn[j]; }
    }

    const float s_pp = ppbuf[cls * P + lane];   // lane p owns proto p

    float probA; int bidxA;
    box_epilogue(dotA, l1A, ffA, s_pp, lane, probA, bidxA);
    out[(size_t)N + (size_t)n0 * P + lane] = probA;
    if (lane == 0) out[n0] = (float)proto_labels[cls * P + bidxA];

    if (v1) {
        float probB; int bidxB;
        box_epilogue(dotB, l1B, ffB, s_pp, lane, probB, bidxB);
        out[(size_t)N + (size_t)n1 * P + lane] = probB;
        if (lane == 0) out[n1] = (float)proto_labels[cls * P + bidxB];
    }
}

extern "C" void kernel_launch(void* const* d_in, const int* in_sizes, int n_in,
                              void* d_out, int out_size, void* d_ws, size_t ws_size,
                              hipStream_t stream) {
    const float* feats        = (const float*)d_in[0];
    const float* protos       = (const float*)d_in[1];
    const int*   cls_ids      = (const int*)d_in[2];
    const int*   proto_labels = (const int*)d_in[3];
    float* out = (float*)d_out;

    const int N    = in_sizes[2];           // 4096
    const int rows = in_sizes[1] / D;       // C*P = 6400
    const int C    = rows / P;              // 100
    const int Gmax = (N + C * (NB - 1)) / NB;

    // Workspace: pp[rows] f32 | gcount[1] | slots[Gmax*NB] | pad | protosT[C*D*P]
    float* pp     = (float*)d_ws;
    int*   gcount = (int*)(pp + rows);
    int*   slots  = gcount + 1;
    size_t off = (size_t)rows * 4 + 4 + (size_t)Gmax * NB * 4;
    off = (off + 255) & ~(size_t)255;
    float* protosT = (float*)((char*)d_ws + off);

    const int normBlocks = (rows + WPB - 1) / WPB;        // 1600
    const int mainBlocks = (Gmax + WPB - 1) / WPB;        // ~537

    prep_kernel<<<normBlocks + 1, 256, 0, stream>>>(
        protos, pp, protosT, rows, cls_ids, slots, gcount, N, C, normBlocks);
    proto_probs_kernel<<<mainBlocks, WPB * 64, 0, stream>>>(
        feats, protosT, cls_ids, proto_labels, pp, slots, gcount, out, N);
}